// Round 13
// baseline (332.796 us; speedup 1.0000x reference)
//
#include <hip/hip_runtime.h>
#include <math.h>
#include <stdint.h>

// ---- problem constants ----
#define NHEAD 16
#define HIDDIM 2048
#define QLRANK 1536
#define KVRANK 512
#define DROT 64
#define BB 2
#define TT 2048
#define BTOK (BB*TT)      // 4096 tokens
#define NPROJ 2304        // fused qlat(1536) + ckv(512) + rot(64), padded
#define CKV0 1536         // ckv base col in fused proj
#define ROT0 2048         // k_rot base col in fused proj

typedef __bf16 bf16x8 __attribute__((ext_vector_type(8)));
typedef __bf16 bf16x4 __attribute__((ext_vector_type(4)));
typedef float f32x4 __attribute__((ext_vector_type(4)));
typedef uint16_t u16;
typedef uint32_t u32;

__device__ __forceinline__ u16 f2bf(float f) {
  union { float f; uint32_t u; } v; v.f = f;
  uint32_t r = v.u + 0x7fffu + ((v.u >> 16) & 1u);
  return (u16)(r >> 16);
}
__device__ __forceinline__ float bf2f(u16 h) {
  union { uint32_t u; float f; } v; v.u = ((uint32_t)h) << 16;
  return v.f;
}

__device__ __forceinline__ void gload_lds16(const u16* g, u16* l) {
  __builtin_amdgcn_global_load_lds(
      (const __attribute__((address_space(1))) uint32_t*)g,
      (__attribute__((address_space(3))) uint32_t*)l, 16, 0, 0);
}

// ---------- elementwise fp32 -> bf16 ----------
__global__ __launch_bounds__(256) void cvt_f32_bf16(const float* __restrict__ in,
                                                    u16* __restrict__ out, int n) {
  int idx = (blockIdx.x * 256 + threadIdx.x) * 8;
  if (idx >= n) return;
  f32x4 a = *(const f32x4*)&in[idx];
  f32x4 b = *(const f32x4*)&in[idx + 4];
  union { f32x4 q; u16 e[8]; } w;
#pragma unroll
  for (int j = 0; j < 4; ++j) { w.e[j] = f2bf(a[j]); w.e[4 + j] = f2bf(b[j]); }
  *(f32x4*)&out[idx] = w.q;
}

// ---------- W[K][N] fp32 -> Wt[Npad][K] bf16 * scale * svec[k] ----------
__global__ __launch_bounds__(256) void transpose_w(const float* __restrict__ W,
                                                   u16* __restrict__ Wt,
                                                   int K, int N, int Npad, float scale,
                                                   const float* __restrict__ svec) {
  __shared__ float tile[32][33];
  int k0 = blockIdx.x * 32, n0 = blockIdx.y * 32;
  int tx = threadIdx.x, ty = threadIdx.y;   // 32 x 8
#pragma unroll
  for (int r = 0; r < 32; r += 8) {
    int k = k0 + ty + r, n = n0 + tx;
    tile[ty + r][tx] = (k < K && n < N) ? W[(size_t)k * N + n] : 0.f;
  }
  __syncthreads();
  float sv = scale * (svec ? svec[k0 + tx] : 1.f);
#pragma unroll
  for (int r = 0; r < 32; r += 8) {
    int n = n0 + ty + r, k = k0 + tx;
    if (n < Npad && k < K) Wt[(size_t)n * K + k] = f2bf(tile[tx][ty + r] * sv);
  }
}

// ---------- per-row inv-rms ----------
template<int D>
__global__ __launch_bounds__(256) void row_invrms(const u16* __restrict__ in, int stride,
                                                  float* __restrict__ out) {
  const int row = blockIdx.x;
  const int tid = threadIdx.x;
  constexpr int NC = D / 8;
  float ss = 0.f;
  if (tid < NC) {
    union { f32x4 q; u16 e[8]; } t;
    t.q = *(const f32x4*)&in[(size_t)row * stride + tid * 8];
#pragma unroll
    for (int j = 0; j < 8; ++j) { float v = bf2f(t.e[j]); ss += v * v; }
  }
#pragma unroll
  for (int off = 1; off < 64; off <<= 1) ss += __shfl_xor(ss, off);
  __shared__ float red[4];
  if ((tid & 63) == 0) red[tid >> 6] = ss;
  __syncthreads();
  if (tid == 0)
    out[row] = rsqrtf((red[0] + red[1] + red[2] + red[3]) / (float)D + 1e-6f);
}

// ---------- GEMM 256x128, BK=32, 8 waves, counted-vmcnt 2-phase dbuf ----------
// 1.4x MFMA per staged byte vs 128^2 (24KB staged -> 128 wave-MFMAs per K-step).
// Staging: 24 chunks of 16 rows x 32 cols over [A(256) | B(128)] stack; 3 chunks/wave,
// each one gload_lds16 (lane -> row c*16+(lane>>2), col (lane&3)*8). vmcnt(3) ledger.
template<int OUTF32>
__global__ __launch_bounds__(512) void gemm_bt2(const u16* __restrict__ A, int lda,
                                                const u16* __restrict__ Bt,
                                                void* __restrict__ Cv, int ldc,
                                                const float* __restrict__ rowscale,
                                                int N, int K) {
  __shared__ __align__(16) u16 S[2][384 * 32];   // 48KB: A rows 0-255, B rows 256-383
  const int tid = threadIdx.x;
  const int lane = tid & 63;
  const int wave = tid >> 6;
  const int l15 = lane & 15, l4 = lane >> 4;
  const int bm = blockIdx.y * 256;
  const int bn = blockIdx.x * 128;
  const int wm = wave >> 1;       // 0..3 -> 64-row strip
  const int wn = wave & 1;        // 0..1 -> 64-col strip

  f32x4 acc[4][4] = {};

  // staging chunk sources
  const u16* sp[3];
#pragma unroll
  for (int j = 0; j < 3; ++j) {
    int c = wave * 3 + j;
    int crow = c * 16 + (lane >> 2);
    int ccol = (lane & 3) * 8;
    if (c < 16) sp[j] = A + (size_t)(bm + crow) * lda + ccol;
    else        sp[j] = Bt + (size_t)(bn + crow - 256) * K + ccol;
  }
  auto stage = [&](int t, int buf) {
    const int k0 = t << 5;
#pragma unroll
    for (int j = 0; j < 3; ++j)
      gload_lds16(sp[j] + k0, &S[buf][(wave * 3 + j) * 512]);
  };

  const int a_off = (wm * 64 + l15) * 32 + l4 * 8;
  const int b_off = 256 * 32 + (wn * 64 + l15) * 32 + l4 * 8;

  const int nt = K >> 5;

  stage(0, 0);
  if (nt > 1) {
    stage(1, 1);
    asm volatile("s_waitcnt vmcnt(3)" ::: "memory");
  } else {
    asm volatile("s_waitcnt vmcnt(0)" ::: "memory");
  }
  __builtin_amdgcn_s_barrier();
  __builtin_amdgcn_sched_barrier(0);

  int cur = 0;
  for (int t = 0; t < nt; ++t) {
    bf16x8 af[4], bfr[4];
#pragma unroll
    for (int m = 0; m < 4; ++m) af[m] = *(const bf16x8*)&S[cur][a_off + m * 16 * 32];
#pragma unroll
    for (int n = 0; n < 4; ++n) bfr[n] = *(const bf16x8*)&S[cur][b_off + n * 16 * 32];
    asm volatile("s_waitcnt lgkmcnt(0)" ::: "memory");
    __builtin_amdgcn_sched_barrier(0);
    __builtin_amdgcn_s_barrier();          // all waves done reading buf[cur]
    if (t + 2 < nt) stage(t + 2, cur);     // overwrite cur with t+2
    __builtin_amdgcn_s_setprio(1);
#pragma unroll
    for (int m = 0; m < 4; ++m)
#pragma unroll
      for (int n = 0; n < 4; ++n)
        acc[m][n] = __builtin_amdgcn_mfma_f32_16x16x32_bf16(af[m], bfr[n], acc[m][n], 0, 0, 0);
    __builtin_amdgcn_s_setprio(0);
    if (t + 1 < nt) {
      if (t + 2 < nt) asm volatile("s_waitcnt vmcnt(3)" ::: "memory");
      else            asm volatile("s_waitcnt vmcnt(0)" ::: "memory");
      __builtin_amdgcn_s_barrier();        // t+1 visible to all waves
      __builtin_amdgcn_sched_barrier(0);
      cur ^= 1;
    }
  }

  const int row0 = bm + wm * 64 + l4 * 4;
  const int col0 = bn + wn * 64 + l15;
#pragma unroll
  for (int m = 0; m < 4; ++m) {
    float rs[4] = {1.f, 1.f, 1.f, 1.f};
    if (rowscale) {
#pragma unroll
      for (int i = 0; i < 4; ++i) rs[i] = rowscale[row0 + m * 16 + i];
    }
#pragma unroll
    for (int n = 0; n < 4; ++n)
#pragma unroll
      for (int i = 0; i < 4; ++i) {
        size_t idx = (size_t)(row0 + m * 16 + i) * ldc + (col0 + n * 16);
        float v = acc[m][n][i] * rs[i];
        if (OUTF32) ((float*)Cv)[idx] = v;
        else        ((u16*)Cv)[idx] = f2bf(v);
      }
  }
}

// ---------- fused q/kv GEMM: 8-phase 256^2 kernel, per-block section select ----------
// blockIdx.x < 12 : q  = rms(qlat) @ wqb   (K=1536, C=q, ldc=3072, rs=invq)
// blockIdx.x >= 12: kv = rms(ckv)  @ wkvb  (K=512,  C=kv, ldc=4096, rs=invkv)
// One 448-block dispatch packs both (vs 192+256 serial under-filled dispatches).
__global__ __launch_bounds__(512, 1) void gemm8p_qkv(const u16* __restrict__ proj,
                                                     const u16* __restrict__ wqb_t,
                                                     u16* __restrict__ qout,
                                                     const float* __restrict__ invq,
                                                     const u16* __restrict__ wkvb_t,
                                                     u16* __restrict__ kvout,
                                                     const float* __restrict__ invkv) {
  const int bx = blockIdx.x;
  const int sec = (bx >= 12);
  const u16* A  = sec ? proj + CKV0 : proj;
  const u16* Bt = sec ? wkvb_t : wqb_t;
  u16* Cv       = sec ? kvout : qout;
  const float* rowscale = sec ? invkv : invq;
  const int ldc = sec ? 4096 : 3072;
  const int K   = sec ? KVRANK : QLRANK;
  const int lda = NPROJ;
  const int bn  = (sec ? (bx - 12) : bx) * 256;
  const int bm  = blockIdx.y * 256;

  __shared__ __align__(16) u16 S[65536];   // 128KB: [buf2][mat2][half2][8192 u16]
  const int tid = threadIdx.x, lane = tid & 63, wave = tid >> 6;
  const int l15 = lane & 15, l4 = lane >> 4;
  const int wm = wave >> 2, wn = wave & 3, wh = wn >> 1;

  int rowc[2], colc[2];
#pragma unroll
  for (int c = 0; c < 2; ++c) {
    int o = c * 8192 + tid * 16;
    int row = o >> 7;
    int slot = (o >> 4) & 7;
    rowc[c] = row;
    colc[c] = (slot ^ (row & 7)) * 8;
  }
  const u16* pa[2][2];
  const u16* pb[2][2];
#pragma unroll
  for (int h = 0; h < 2; ++h)
#pragma unroll
    for (int c = 0; c < 2; ++c) {
      pa[h][c] = A  + (size_t)(bm + h * 128 + rowc[c]) * lda + colc[c];
      pb[h][c] = Bt + (size_t)(bn + h * 128 + rowc[c]) * K   + colc[c];
    }
  auto stA = [&](int h, int t) {
    u16* d = &S[(((t & 1) * 2 + 0) * 2 + h) * 8192 + tid * 8];
    gload_lds16(pa[h][0] + t * 64, d);
    gload_lds16(pa[h][1] + t * 64, d + 4096);
  };
  auto stB = [&](int h, int t) {
    u16* d = &S[(((t & 1) * 2 + 1) * 2 + h) * 8192 + tid * 8];
    gload_lds16(pb[h][0] + t * 64, d);
    gload_lds16(pb[h][1] + t * 64, d + 4096);
  };

  const char* Sc = (const char*)S;
  const int sw = l15 & 7;
  const int sl0 = ((0 + l4) ^ sw) * 16;
  const int sl1 = ((4 + l4) ^ sw) * 16;
  const int aoff = (0 * 2 + wm) * 16384 + l15 * 128;
  const int boff = (1 * 2 + wh) * 16384 + ((wn & 1) * 64 + l15) * 128;

  f32x4 acc[8][4] = {};
  const int nt = K >> 6;

  stA(0, 0); stA(1, 0); stB(0, 0); stB(1, 0);
  if (nt > 1) {
    stB(0, 1); stB(1, 1);
    asm volatile("s_waitcnt vmcnt(4)" ::: "memory");
  } else {
    asm volatile("s_waitcnt vmcnt(0)" ::: "memory");
  }
  __builtin_amdgcn_s_barrier();
  __builtin_amdgcn_sched_barrier(0);

  for (int t = 0; t < nt; ++t) {
    const int buf = (t & 1) * 65536;
    bf16x8 bfr[4][2];
#pragma unroll
    for (int q = 0; q < 4; ++q) {
      bf16x8 afr[2][2];
#pragma unroll
      for (int m2 = 0; m2 < 2; ++m2) {
        const int fo = buf + aoff + (2 * q + m2) * 2048;
        afr[m2][0] = *(const bf16x8*)(Sc + fo + sl0);
        afr[m2][1] = *(const bf16x8*)(Sc + fo + sl1);
      }
      if (q == 0) {
#pragma unroll
        for (int fn = 0; fn < 4; ++fn) {
          const int fo = buf + boff + fn * 2048;
          bfr[fn][0] = *(const bf16x8*)(Sc + fo + sl0);
          bfr[fn][1] = *(const bf16x8*)(Sc + fo + sl1);
        }
      }
      if (q == 0)      { if (t + 1 < nt) stA(0, t + 1); }
      else if (q == 1) { if (t + 1 < nt) stA(1, t + 1); }
      else if (q == 2) { if (t + 2 < nt) stB(0, t + 2); }
      else             { if (t + 2 < nt) stB(1, t + 2); }

      __builtin_amdgcn_s_barrier();
      asm volatile("s_waitcnt lgkmcnt(0)" ::: "memory");
      __builtin_amdgcn_sched_barrier(0);
      __builtin_amdgcn_s_setprio(1);
#pragma unroll
      for (int m2 = 0; m2 < 2; ++m2)
#pragma unroll
        for (int fn = 0; fn < 4; ++fn) {
          f32x4 c = acc[2 * q + m2][fn];
          c = __builtin_amdgcn_mfma_f32_16x16x32_bf16(afr[m2][0], bfr[fn][0], c, 0, 0, 0);
          c = __builtin_amdgcn_mfma_f32_16x16x32_bf16(afr[m2][1], bfr[fn][1], c, 0, 0, 0);
          acc[2 * q + m2][fn] = c;
        }
      __builtin_amdgcn_s_setprio(0);
      __builtin_amdgcn_s_barrier();
      __builtin_amdgcn_sched_barrier(0);
    }
    if (t + 1 < nt) {
      if (t + 2 < nt) asm volatile("s_waitcnt vmcnt(4)" ::: "memory");
      else            asm volatile("s_waitcnt vmcnt(0)" ::: "memory");
      __builtin_amdgcn_s_barrier();
      __builtin_amdgcn_sched_barrier(0);
    }
  }

  const int row0 = bm + wm * 128 + l4 * 4;
  const int col0 = bn + wn * 64 + l15;
#pragma unroll
  for (int fm = 0; fm < 8; ++fm) {
    float rs[4];
#pragma unroll
    for (int i = 0; i < 4; ++i) rs[i] = rowscale[row0 + fm * 16 + i];
#pragma unroll
    for (int fn = 0; fn < 4; ++fn)
#pragma unroll
      for (int i = 0; i < 4; ++i) {
        size_t idx = (size_t)(row0 + fm * 16 + i) * ldc + (col0 + fn * 16);
        Cv[idx] = f2bf(acc[fm][fn][i] * rs[i]);
      }
  }
}

// ---------- RoPE cos/sin table ----------
__global__ __launch_bounds__(256) void rope_table(const int* __restrict__ positions,
                                                  float2* __restrict__ tab) {
  int idx = blockIdx.x * 256 + threadIdx.x;
  if (idx >= BTOK * 32) return;
  int bt = idx >> 5, i = idx & 31;
  float invf = powf(10000.0f, -(float)i / 32.0f);
  float ang = (float)positions[bt] * invf;
  tab[idx] = make_float2(cosf(ang), sinf(ang));
}

// ---------- RoPE on q_rot in place ----------
__global__ __launch_bounds__(256) void rope_q(u16* __restrict__ q,
                                              const float2* __restrict__ tab) {
  int idx = blockIdx.x * 256 + threadIdx.x;
  if (idx >= BTOK * NHEAD * 32) return;
  int i = idx & 31;
  int h = (idx >> 5) & 15;
  int bt = idx >> 9;
  u16* p = q + (size_t)bt * 3072 + h * 192 + 128;
  float x1 = bf2f(p[i]), x2 = bf2f(p[32 + i]);
  float2 cs = tab[bt * 32 + i];
  p[i] = f2bf(x1 * cs.x - x2 * cs.y);
  p[32 + i] = f2bf(x2 * cs.x + x1 * cs.y);
}

// ---------- RoPE k_rot -> rot[bt][64] ----------
__global__ __launch_bounds__(256) void rope_k(const u16* __restrict__ proj,
                                              const float2* __restrict__ tab,
                                              u16* __restrict__ rot) {
  int idx = blockIdx.x * 256 + threadIdx.x;   // BT*32
  if (idx >= BTOK * 32) return;
  int bt = idx >> 5, i = idx & 31;
  float2 cs = tab[bt * 32 + i];
  float x1 = bf2f(proj[(size_t)bt * NPROJ + ROT0 + i]);
  float x2 = bf2f(proj[(size_t)bt * NPROJ + ROT0 + 32 + i]);
  rot[bt * 64 + i]      = f2bf(x1 * cs.x - x2 * cs.y);
  rot[bt * 64 + 32 + i] = f2bf(x2 * cs.x + x1 * cs.y);
}

// ---------- job table ----------
__device__ const int8_t JOB_QT[24] = {15,15,7,14,14,13,13,6,12,12,11,11,5,10,10,9,9,4,8,8,3,2,1,0};
__device__ const int8_t JOB_PC[24] = { 0, 1,2, 0, 1, 0, 1,2, 0, 1, 0, 1,2, 0, 1,0,1,2,0,1,2,2,2,2};

// ---------- causal flash attention v7 (round-12 proven) ----------
__global__ __launch_bounds__(256, 2) void attn_fwd7(const u16* __restrict__ Q,
                                                    const u16* __restrict__ Rot,
                                                    const u16* __restrict__ KV,
                                                    u16* __restrict__ O,
                                                    u16* __restrict__ Opart,
                                                    float2* __restrict__ ml) {
  __shared__ __align__(16) u16 Ks[64 * 192];     // 24KB, XOR-swizzled
  __shared__ __align__(16) u16 Vs[64 * 128];     // 16KB, tr-subtile, identity key order
  __shared__ __align__(16) u16 Ps[4][32][72];    // 18KB, rows=q, cols=key (identity)

  const int tid = threadIdx.x, lane = tid & 63, wave = tid >> 6;
  const int l15 = lane & 15, l4 = lane >> 4;
  const int jobrank = blockIdx.x >> 5;
  const int bh = blockIdx.x & 31;
  const int qt = JOB_QT[jobrank];
  const int piece = JOB_PC[jobrank];
  const int q0 = qt * 128;
  const int b = bh >> 4, h = bh & 15;
  const int wq0 = q0 + wave * 32;

  bf16x8 qf[2][6];
#pragma unroll
  for (int m = 0; m < 2; ++m) {
    const u16* qp = Q + (size_t)(b * TT + wq0 + m * 16 + l15) * 3072 + h * 192 + l4 * 8;
#pragma unroll
    for (int kk = 0; kk < 6; ++kk) qf[m][kk] = *(const bf16x8*)(qp + kk * 32);
  }

  const int kt0 = (piece == 1) ? (qt + 1) : 0;
  const int kt1 = (piece == 0) ? (qt + 1) : (2 * qt + 2);

  const u16* kvb  = KV + (size_t)(b * TT) * 4096 + h * 256;
  const u16* rotb = Rot + (size_t)(b * TT) * 64;
  const u16* kp[6];
  int kstep[6];
#pragma unroll
  for (int j = 0; j < 6; ++j) {
    int o = (wave * 6 + j) * 1024 + lane * 16;
    int row = o / 384, col = o % 384;
    int scol = col ^ ((row & 7) << 4);
    if (scol < 256) { kp[j] = kvb + row * 4096 + (scol >> 1);          kstep[j] = 64 * 4096; }
    else            { kp[j] = rotb + row * 64 + ((scol >> 1) - 128);   kstep[j] = 64 * 64; }
    kp[j] += (size_t)kt0 * kstep[j];
  }
  int vsrc[4];
#pragma unroll
  for (int j = 0; j < 4; ++j) {
    int lam = (wave * 4 + j) * 512 + lane * 8;
    int kap = ((lam >> 6) & 15) * 4 + ((lam >> 4) & 3);
    int key = ((kap >> 5) & 1) * 32 + ((kap >> 2) & 3) * 8 + ((kap >> 4) & 1) * 4 + (kap & 3);
    int dv  = (lam >> 10) * 16 + (lam & 15);
    vsrc[j] = key * 4096 + dv;
  }
  const u16* Vbase = KV + (size_t)(b * TT) * 4096 + h * 256 + 128;
  u16* KsW = Ks + (wave * 6) * 512;
  u16* VsW = Vs + (wave * 4) * 512;
  const unsigned vs_base = (unsigned)(uintptr_t)(&Vs[0]);

  f32x4 o_acc[2][8] = {};
  float m_r[2], l_r[2];
#pragma unroll
  for (int m = 0; m < 2; ++m) { m_r[m] = -INFINITY; l_r[m] = 0.f; }

  for (int kt = kt0; kt < kt1; ++kt) {
    __syncthreads();
    const u16* Vt = Vbase + (size_t)(kt * 64) * 4096;
#pragma unroll
    for (int j = 0; j < 6; ++j) { gload_lds16(kp[j], KsW + j * 512); kp[j] += kstep[j]; }
#pragma unroll
    for (int j = 0; j < 4; ++j) gload_lds16(Vt + vsrc[j], VsW + j * 512);
    __syncthreads();

    if (kt * 64 > wq0 + 31) continue;
    const int kt64 = kt * 64;

    // ---- S^T = K Q^T (swapped operands) ----
    f32x4 s[2][4] = {};
    __builtin_amdgcn_s_setprio(1);
#pragma unroll
    for (int n = 0; n < 4; ++n) {
      const int krow = n * 16 + l15;
      const int swz = (l15 & 7) << 3;
#pragma unroll
      for (int kk = 0; kk < 6; ++kk) {
        bf16x8 kb = *(const bf16x8*)&Ks[krow * 192 + ((kk * 32 + l4 * 8) ^ swz)];
        s[0][n] = __builtin_amdgcn_mfma_f32_16x16x32_bf16(kb, qf[0][kk], s[0][n], 0, 0, 0);
        s[1][n] = __builtin_amdgcn_mfma_f32_16x16x32_bf16(kb, qf[1][kk], s[1][n], 0, 0, 0);
      }
    }
    __builtin_amdgcn_s_setprio(0);

    // ---- online softmax ----
#pragma unroll
    for (int m = 0; m < 2; ++m) {
      const int qrow = wq0 + m * 16 + l15;
      const bool needmask = (kt64 + 63) > (wq0 + m * 16);
      if (needmask) {
#pragma unroll
        for (int n = 0; n < 4; ++n)
#pragma unroll
          for (int i = 0; i < 4; ++i)
            if (kt64 + n * 16 + l4 * 4 + i > qrow) s[m][n][i] = -INFINITY;
      }
      float pmax = -INFINITY;
#pragma unroll
      for (int n = 0; n < 4; ++n)
#pragma unroll
        for (int i = 0; i < 4; ++i) pmax = fmaxf(pmax, s[m][n][i]);
      pmax = fmaxf(pmax, __shfl_xor(pmax, 16));
      pmax = fmaxf(pmax, __shfl_xor(pmax, 32));

      if (!__all(pmax - m_r[m] <= 8.f)) {        // defer-max (THR=8)
        float mn = fmaxf(m_r[m], pmax);
        float alpha = __expf(m_r[m] - mn);
        m_r[m] = mn;
        l_r[m] *= alpha;
        float ab[4];
#pragma unroll
        for (int i = 0; i < 4; ++i) ab[i] = __shfl(alpha, l4 * 4 + i);
#pragma unroll
        for (int n = 0; n < 8; ++n)
#pragma unroll
          for (int i = 0; i < 4; ++i) o_acc[m][n][i] *= ab[i];
      }

      float psum = 0.f;
#pragma unroll
      for (int n = 0; n < 4; ++n) {
        float p0 = __expf(s[m][n][0] - m_r[m]);
        float p1 = __expf(s[m][n][1] - m_r[m]);
        float p2 = __expf(s[m][n][2] - m_r[m]);
        float p3 = __expf(s[m][n][3] - m_r[m]);
        psum += (p0 + p1) + (p2 + p3);
        union { uint2 d; u16 e[4]; } pw;
        pw.e[0] = f2bf(p0); pw.e[1] = f2bf(p1);
        pw.e[2] = f2bf(p2); pw.e[3] = f2bf(p3);
        *(uint2*)&Ps[wave][m * 16 + l15][n * 16 + l4 * 4] = pw.d;
      }
      psum += __shfl_xor(psum, 16);
      psum += __shfl_xor(psum, 32);
      l_r[m] += psum;
    }

    asm volatile("s_waitcnt lgkmcnt(0)" ::: "memory");
    __builtin_amdgcn_sched_barrier(0);

    // ---- O += P V ----
#pragma unroll
    for (int kk = 0; kk < 2; ++kk) {
      bf16x8 pa[2];
      pa[0] = *(const bf16x8*)&Ps[wave][l15][kk * 32 + l4 * 8];
      pa[1] = *(const bf16x8*)&Ps[wave][16 + l15][kk * 32 + l4 * 8];
      const unsigned va = vs_base + kk * 1024 + lane * 8;
#pragma unroll
      for (int g = 0; g < 2; ++g) {
        union { uint2 u; bf16x4 b; } lo[4], hi[4];
#pragma unroll
        for (int n = 0; n < 4; ++n) {
          unsigned a0 = va + (g * 4 + n) * 2048;
          asm volatile("ds_read_b64_tr_b16 %0, %1" : "=v"(lo[n].u) : "v"(a0));
          asm volatile("ds_read_b64_tr_b16 %0, %1 offset:512" : "=v"(hi[n].u) : "v"(a0));
        }
        asm volatile("s_waitcnt lgkmcnt(0)" ::: "memory");
        __builtin_amdgcn_sched_barrier(0);
        __builtin_amdgcn_s_setprio(1);
#pragma unroll
        for (int n = 0; n < 4; ++n) {
          bf16x8 vb = __builtin_shufflevector(lo[n].b, hi[n].b, 0, 1, 2, 3, 4, 5, 6, 7);
          o_acc[0][g * 4 + n] = __builtin_amdgcn_mfma_f32_16x16x32_bf16(pa[0], vb, o_acc[0][g * 4 + n], 0, 0, 0);
          o_acc[1][g * 4 + n] = __builtin_amdgcn_mfma_f32_16x16x32_bf16(pa[1], vb, o_acc[1][g * 4 + n], 0, 0, 0);
        }
        __builtin_amdgcn_s_setprio(0);
      }
    }
  }

  if (piece == 2) {
#pragma unroll
    for (int m = 0; m < 2; ++m) {
      float inv = 1.f / l_r[m];
      float li[4];
#pragma unroll
      for (int i = 0; i < 4; ++i) li[i] = __shfl(inv, l4 * 4 + i);
#pragma unroll
      for (int n = 0; n < 8; ++n)
#pragma unroll
        for (int i = 0; i < 4; ++i) {
          int r = wq0 + m * 16 + l4 * 4 + i;
          O[(size_t)(b * TT + r) * 2048 + h * 128 + n * 16 + l15] = f2bf(o_acc[m][n][i] * li[i]);
        }
    }
  } else {
    const size_t pidx = ((size_t)(qt - 8) * 32 + bh) * 2 + piece;
    u16* op = Opart + pidx * (128 * 128);
    float2* mlp = ml + pidx * 128;
#pragma unroll
    for (int m = 0; m < 2; ++m)
#pragma unroll
      for (int n = 0; n < 8; ++n)
#pragma unroll
        for (int i = 0; i < 4; ++i)
          op[(wave * 32 + m * 16 + l4 * 4 + i) * 128 + n * 16 + l15] = f2bf(o_acc[m][n][i]);
    if (l4 == 0) {
#pragma unroll
      for (int m = 0; m < 2; ++m)
        mlp[wave * 32 + m * 16 + l15] = make_float2(m_r[m], l_r[m]);
    }
  }
}

// ---------- combine split pieces ----------
__global__ __launch_bounds__(256) void attn_combine(const u16* __restrict__ Opart,
                                                    const float2* __restrict__ ml,
                                                    u16* __restrict__ O) {
  int gid = blockIdx.x * 256 + threadIdx.x;
  int dvseg = gid & 15;
  int row = (gid >> 4) & 127;
  int bh = (gid >> 11) & 31;
  int qt8 = gid >> 16;
  size_t i1 = ((size_t)qt8 * 32 + bh) * 2;
  float2 ml1 = ml[i1 * 128 + row], ml2 = ml[(i1 + 1) * 128 + row];
  float m = fmaxf(ml1.x, ml2.x);
  float w1 = __expf(ml1.x - m), w2 = __expf(ml2.x - m);
  float inv = 1.f / (w1 * ml1.y + w2 * ml2.y);
  union { f32x4 q; u16 e[8]; } a, bq, w;
  a.q  = *(const f32x4*)&Opart[i1 * 16384 + row * 128 + dvseg * 8];
  bq.q = *(const f32x4*)&Opart[(i1 + 1) * 16384 + row * 128 + dvseg * 8];
#pragma unroll
  for (int j = 0; j < 8; ++j)
    w.e[j] = f2bf((w1 * bf2f(a.e[j]) + w2 * bf2f(bq.e[j])) * inv);
  int b = bh >> 4, h = bh & 15;
  int r = 1024 + qt8 * 128 + row;
  *(f32x4*)&O[(size_t)(b * TT + r) * 2048 + h * 128 + dvseg * 8] = w.q;
}

extern "C" void kernel_launch(void* const* d_in, const int* in_sizes, int n_in,
                              void* d_out, int out_size, void* d_ws, size_t ws_size,
                              hipStream_t stream) {
  (void)in_sizes; (void)n_in; (void)out_size; (void)ws_size;
  const float* x         = (const float*)d_in[0];
  const int*   positions = (const int*)d_in[2];
  const float* wqa       = (const float*)d_in[3];
  const float* qa_scale  = (const float*)d_in[4];
  const float* wqb       = (const float*)d_in[5];
  const float* wkva      = (const float*)d_in[6];
  const float* kva_scale = (const float*)d_in[7];
  const float* wkvb      = (const float*)d_in[8];
  const float* wo        = (const float*)d_in[9];
  float* out = (float*)d_out;

  char* wsp = (char*)d_ws;
  auto alloc = [&](size_t bytes) {
    char* p = wsp; wsp += (bytes + 255) & ~(size_t)255; return p;
  };
  u16* xb      = (u16*)alloc((size_t)BTOK * HIDDIM * 2);       // x bf16; reused as attn O
  u16* proj_t  = (u16*)alloc((size_t)NPROJ * HIDDIM * 2);      // [wqa_t | wkva_t | pad]
  u16* wqb_t   = (u16*)alloc((size_t)3072 * QLRANK * 2);       // qa_scale*qscale folded
  u16* wkvb_t  = (u16*)alloc((size_t)4096 * KVRANK * 2);       // kva_scale folded
  u16* wo_t    = (u16*)alloc((size_t)HIDDIM * HIDDIM * 2);
  u16* proj    = (u16*)alloc((size_t)BTOK * NPROJ * 2);        // [qlat | ckv | rot | pad]
  u16* q       = (u16*)alloc((size_t)BTOK * 3072 * 2);
  u16* kv      = (u16*)alloc((size_t)BTOK * 4096 * 2);
  u16* rot     = (u16*)alloc((size_t)BTOK * 64 * 2);           // roped k_rot
  float2* tab  = (float2*)alloc((size_t)BTOK * 32 * 8);
  float* invq  = (float*)alloc((size_t)BTOK * 4);
  float* invkv = (float*)alloc((size_t)BTOK * 4);
  float2* mlbuf= (float2*)alloc((size_t)8 * 32 * 2 * 128 * 8);
  u16* ao = xb;          // xb dead after proj GEMM
  u16* Opart = proj;     // proj dead after gemm_qkv/rope_k

  dim3 blk(256);
  dim3 blk512(512);
  const float qscale = 0.07216878364870322f;   // 192^-0.5, folded into wqb

  cvt_f32_bf16<<<(BTOK * HIDDIM / 8 + 255) / 256, blk, 0, stream>>>(x, xb, BTOK * HIDDIM);
  {
    dim3 tb(32, 8);
    transpose_w<<<dim3(HIDDIM / 32, QLRANK / 32), tb, 0, stream>>>(wqa, proj_t, HIDDIM, QLRANK, QLRANK, 1.f, nullptr);
    transpose_w<<<dim3(HIDDIM / 32, (NPROJ - CKV0) / 32), tb, 0, stream>>>(wkva, proj_t + (size_t)CKV0 * HIDDIM, HIDDIM, 576, NPROJ - CKV0, 1.f, nullptr);
    transpose_w<<<dim3(QLRANK / 32, 3072 / 32), tb, 0, stream>>>(wqb, wqb_t, QLRANK, 3072, 3072, qscale, qa_scale);
    transpose_w<<<dim3(KVRANK / 32, 4096 / 32), tb, 0, stream>>>(wkvb, wkvb_t, KVRANK, 4096, 4096, 1.f, kva_scale);
    transpose_w<<<dim3(HIDDIM / 32, HIDDIM / 32), tb, 0, stream>>>(wo, wo_t, HIDDIM, HIDDIM, HIDDIM, 1.f, nullptr);
  }
  rope_table<<<(BTOK * 32 + 255) / 256, blk, 0, stream>>>(positions, tab);

  // fused projection (288 blocks @256x128, counted-vmcnt, 8 waves)
  gemm_bt2<0><<<dim3(NPROJ / 128, BTOK / 256), blk512, 0, stream>>>(xb, HIDDIM, proj_t, proj, NPROJ, nullptr, NPROJ, HIDDIM);

  row_invrms<QLRANK><<<BTOK, blk, 0, stream>>>(proj, NPROJ, invq);
  row_invrms<KVRANK><<<BTOK, blk, 0, stream>>>(proj + CKV0, NPROJ, invkv);

  // fused q+kv GEMM: one 448-block 8-phase dispatch (12 long-K + 16 short-K columns)
  gemm8p_qkv<<<dim3(28, BTOK / 256), blk512, 0, stream>>>(proj, wqb_t, q, invq, wkvb_t, kv, invkv);

  rope_q<<<(BTOK * NHEAD * 32 + 255) / 256, blk, 0, stream>>>(q, tab);
  rope_k<<<(BTOK * 32 + 255) / 256, blk, 0, stream>>>(proj, tab, rot);

  attn_fwd7<<<dim3(24 * 32), blk, 0, stream>>>(q, rot, kv, ao, Opart, mlbuf);
  attn_combine<<<(8 * 32 * 128 * 16) / 256, blk, 0, stream>>>(Opart, mlbuf, ao);

  // output projection (256 blocks @256x128, counted-vmcnt, 8 waves)
  gemm_bt2<1><<<dim3(HIDDIM / 128, BTOK / 256), blk512, 0, stream>>>(ao, HIDDIM, wo_t, out, HIDDIM, nullptr, HIDDIM, HIDDIM);
}

// Round 14
// 302.570 us; speedup vs baseline: 1.0999x; 1.0999x over previous
//
#include <hip/hip_runtime.h>
#include <math.h>
#include <stdint.h>

// ---- problem constants ----
#define NHEAD 16
#define HIDDIM 2048
#define QLRANK 1536
#define KVRANK 512
#define DROT 64
#define BB 2
#define TT 2048
#define BTOK (BB*TT)      // 4096 tokens
#define NPROJ 2304        // fused qlat(1536) + ckv(512) + rot(64), padded
#define CKV0 1536         // ckv base col in fused proj
#define ROT0 2048         // k_rot base col in fused proj

typedef __bf16 bf16x8 __attribute__((ext_vector_type(8)));
typedef __bf16 bf16x4 __attribute__((ext_vector_type(4)));
typedef float f32x4 __attribute__((ext_vector_type(4)));
typedef uint16_t u16;
typedef uint32_t u32;

__device__ __forceinline__ u16 f2bf(float f) {
  union { float f; uint32_t u; } v; v.f = f;
  uint32_t r = v.u + 0x7fffu + ((v.u >> 16) & 1u);
  return (u16)(r >> 16);
}
__device__ __forceinline__ float bf2f(u16 h) {
  union { uint32_t u; float f; } v; v.u = ((uint32_t)h) << 16;
  return v.f;
}

__device__ __forceinline__ void gload_lds16(const u16* g, u16* l) {
  __builtin_amdgcn_global_load_lds(
      (const __attribute__((address_space(1))) uint32_t*)g,
      (__attribute__((address_space(3))) uint32_t*)l, 16, 0, 0);
}

// ---------- elementwise fp32 -> bf16 ----------
__global__ __launch_bounds__(256) void cvt_f32_bf16(const float* __restrict__ in,
                                                    u16* __restrict__ out, int n) {
  int idx = (blockIdx.x * 256 + threadIdx.x) * 8;
  if (idx >= n) return;
  f32x4 a = *(const f32x4*)&in[idx];
  f32x4 b = *(const f32x4*)&in[idx + 4];
  union { f32x4 q; u16 e[8]; } w;
#pragma unroll
  for (int j = 0; j < 4; ++j) { w.e[j] = f2bf(a[j]); w.e[4 + j] = f2bf(b[j]); }
  *(f32x4*)&out[idx] = w.q;
}

// ---------- W[K][N] fp32 -> Wt[Npad][K] bf16 * scale * svec[k] ----------
__global__ __launch_bounds__(256) void transpose_w(const float* __restrict__ W,
                                                   u16* __restrict__ Wt,
                                                   int K, int N, int Npad, float scale,
                                                   const float* __restrict__ svec) {
  __shared__ float tile[32][33];
  int k0 = blockIdx.x * 32, n0 = blockIdx.y * 32;
  int tx = threadIdx.x, ty = threadIdx.y;   // 32 x 8
#pragma unroll
  for (int r = 0; r < 32; r += 8) {
    int k = k0 + ty + r, n = n0 + tx;
    tile[ty + r][tx] = (k < K && n < N) ? W[(size_t)k * N + n] : 0.f;
  }
  __syncthreads();
  float sv = scale * (svec ? svec[k0 + tx] : 1.f);
#pragma unroll
  for (int r = 0; r < 32; r += 8) {
    int n = n0 + ty + r, k = k0 + tx;
    if (n < Npad && k < K) Wt[(size_t)n * K + k] = f2bf(tile[tx][ty + r] * sv);
  }
}

// ---------- per-row inv-rms ----------
template<int D>
__global__ __launch_bounds__(256) void row_invrms(const u16* __restrict__ in, int stride,
                                                  float* __restrict__ out) {
  const int row = blockIdx.x;
  const int tid = threadIdx.x;
  constexpr int NC = D / 8;
  float ss = 0.f;
  if (tid < NC) {
    union { f32x4 q; u16 e[8]; } t;
    t.q = *(const f32x4*)&in[(size_t)row * stride + tid * 8];
#pragma unroll
    for (int j = 0; j < 8; ++j) { float v = bf2f(t.e[j]); ss += v * v; }
  }
#pragma unroll
  for (int off = 1; off < 64; off <<= 1) ss += __shfl_xor(ss, off);
  __shared__ float red[4];
  if ((tid & 63) == 0) red[tid >> 6] = ss;
  __syncthreads();
  if (tid == 0)
    out[row] = rsqrtf((red[0] + red[1] + red[2] + red[3]) / (float)D + 1e-6f);
}

// ---------- GEMM 128x128, BK=32, 4 waves, counted-vmcnt 2-phase dbuf (r12 proven) ----------
template<int OUTF32>
__global__ __launch_bounds__(256) void gemm_bt(const u16* __restrict__ A, int lda,
                                               const u16* __restrict__ Bt,
                                               void* __restrict__ Cv, int ldc,
                                               const float* __restrict__ rowscale,
                                               int N, int K) {
  __shared__ __align__(16) u16 As[2][128 * 32];
  __shared__ __align__(16) u16 Bs[2][128 * 32];
  const int tid = threadIdx.x;
  const int lane = tid & 63;
  const int wave = tid >> 6;
  const int bm = blockIdx.y * 128;
  const int bn = blockIdx.x * 128;
  const int wr = wave >> 1;
  const int wc = wave & 1;

  f32x4 acc[4][4] = {};

  const int srow = wave * 16 + (lane >> 2);
  const int scol = (lane & 3) * 8;
  const u16* Ag = A + (size_t)(bm + srow) * lda + scol;
  const u16* Bg = Bt + (size_t)(bn + srow) * K + scol;
  const int soff = (wave * 16) * 32;

  const int a_off = (wr * 64 + (lane & 15)) * 32 + (lane >> 4) * 8;
  const int b_off = (wc * 64 + (lane & 15)) * 32 + (lane >> 4) * 8;

  const int nt = K >> 5;

  auto stage = [&](int t, int buf) {
    const int k0 = t << 5;
    gload_lds16(Ag + k0, &As[buf][soff]);
    gload_lds16(Ag + (size_t)64 * lda + k0, &As[buf][soff + 64 * 32]);
    gload_lds16(Bg + k0, &Bs[buf][soff]);
    gload_lds16(Bg + (size_t)64 * K + k0, &Bs[buf][soff + 64 * 32]);
  };

  stage(0, 0);
  if (nt > 1) {
    stage(1, 1);
    asm volatile("s_waitcnt vmcnt(4)" ::: "memory");
  } else {
    asm volatile("s_waitcnt vmcnt(0)" ::: "memory");
  }
  __builtin_amdgcn_s_barrier();
  __builtin_amdgcn_sched_barrier(0);

  int cur = 0;
  for (int t = 0; t < nt; ++t) {
    bf16x8 af[4], bfr[4];
#pragma unroll
    for (int m = 0; m < 4; ++m) af[m] = *(const bf16x8*)&As[cur][a_off + m * 16 * 32];
#pragma unroll
    for (int n = 0; n < 4; ++n) bfr[n] = *(const bf16x8*)&Bs[cur][b_off + n * 16 * 32];
    asm volatile("s_waitcnt lgkmcnt(0)" ::: "memory");
    __builtin_amdgcn_sched_barrier(0);
    __builtin_amdgcn_s_barrier();          // all waves done reading buf[cur]
    if (t + 2 < nt) stage(t + 2, cur);     // overwrite cur with t+2
    __builtin_amdgcn_s_setprio(1);
#pragma unroll
    for (int m = 0; m < 4; ++m)
#pragma unroll
      for (int n = 0; n < 4; ++n)
        acc[m][n] = __builtin_amdgcn_mfma_f32_16x16x32_bf16(af[m], bfr[n], acc[m][n], 0, 0, 0);
    __builtin_amdgcn_s_setprio(0);
    if (t + 1 < nt) {
      if (t + 2 < nt) asm volatile("s_waitcnt vmcnt(4)" ::: "memory");
      else            asm volatile("s_waitcnt vmcnt(0)" ::: "memory");
      __builtin_amdgcn_s_barrier();        // t+1 visible to all waves
      __builtin_amdgcn_sched_barrier(0);
      cur ^= 1;
    }
  }

  const int row0 = bm + wr * 64 + (lane >> 4) * 4;
  const int col0 = bn + wc * 64 + (lane & 15);
#pragma unroll
  for (int m = 0; m < 4; ++m) {
    float rs[4] = {1.f, 1.f, 1.f, 1.f};
    if (rowscale) {
#pragma unroll
      for (int i = 0; i < 4; ++i) rs[i] = rowscale[row0 + m * 16 + i];
    }
#pragma unroll
    for (int n = 0; n < 4; ++n)
#pragma unroll
      for (int i = 0; i < 4; ++i) {
        size_t idx = (size_t)(row0 + m * 16 + i) * ldc + (col0 + n * 16);
        float v = acc[m][n][i] * rs[i];
        if (OUTF32) ((float*)Cv)[idx] = v;
        else        ((u16*)Cv)[idx] = f2bf(v);
      }
  }
}

// ---------- GEMM 256x256, BK=64, 8 waves, 8-PHASE counted-vmcnt + XCD swizzle ----------
template<int OUTF32>
__global__ __launch_bounds__(512, 1) void gemm8p(const u16* __restrict__ A, int lda,
                                                 const u16* __restrict__ Bt,
                                                 void* __restrict__ Cv, int ldc,
                                                 const float* __restrict__ rowscale,
                                                 int K) {
  __shared__ __align__(16) u16 S[65536];   // 128KB: [buf2][mat2][half2][8192 u16]
  const int tid = threadIdx.x, lane = tid & 63, wave = tid >> 6;
  const int l15 = lane & 15, l4 = lane >> 4;
  // XCD-aware swizzle (T1): nwg % 8 == 0 for all our grids (192, 256).
  const int nwgx = gridDim.x;
  const int nwg = nwgx * gridDim.y;
  int bid = blockIdx.y * nwgx + blockIdx.x;
  bid = (bid & 7) * (nwg >> 3) + (bid >> 3);
  const int bm = (bid / nwgx) * 256, bn = (bid % nwgx) * 256;
  const int wm = wave >> 2, wn = wave & 3, wh = wn >> 1;

  int rowc[2], colc[2];
#pragma unroll
  for (int c = 0; c < 2; ++c) {
    int o = c * 8192 + tid * 16;
    int row = o >> 7;
    int slot = (o >> 4) & 7;
    rowc[c] = row;
    colc[c] = (slot ^ (row & 7)) * 8;
  }
  const u16* pa[2][2];
  const u16* pb[2][2];
#pragma unroll
  for (int h = 0; h < 2; ++h)
#pragma unroll
    for (int c = 0; c < 2; ++c) {
      pa[h][c] = A  + (size_t)(bm + h * 128 + rowc[c]) * lda + colc[c];
      pb[h][c] = Bt + (size_t)(bn + h * 128 + rowc[c]) * K   + colc[c];
    }
  auto stA = [&](int h, int t) {
    u16* d = &S[(((t & 1) * 2 + 0) * 2 + h) * 8192 + tid * 8];
    gload_lds16(pa[h][0] + t * 64, d);
    gload_lds16(pa[h][1] + t * 64, d + 4096);
  };
  auto stB = [&](int h, int t) {
    u16* d = &S[(((t & 1) * 2 + 1) * 2 + h) * 8192 + tid * 8];
    gload_lds16(pb[h][0] + t * 64, d);
    gload_lds16(pb[h][1] + t * 64, d + 4096);
  };

  const char* Sc = (const char*)S;
  const int sw = l15 & 7;
  const int sl0 = ((0 + l4) ^ sw) * 16;
  const int sl1 = ((4 + l4) ^ sw) * 16;
  const int aoff = (0 * 2 + wm) * 16384 + l15 * 128;
  const int boff = (1 * 2 + wh) * 16384 + ((wn & 1) * 64 + l15) * 128;

  f32x4 acc[8][4] = {};
  const int nt = K >> 6;

  stA(0, 0); stA(1, 0); stB(0, 0); stB(1, 0);
  if (nt > 1) {
    stB(0, 1); stB(1, 1);
    asm volatile("s_waitcnt vmcnt(4)" ::: "memory");
  } else {
    asm volatile("s_waitcnt vmcnt(0)" ::: "memory");
  }
  __builtin_amdgcn_s_barrier();
  __builtin_amdgcn_sched_barrier(0);

  for (int t = 0; t < nt; ++t) {
    const int buf = (t & 1) * 65536;
    bf16x8 bfr[4][2];
#pragma unroll
    for (int q = 0; q < 4; ++q) {
      bf16x8 afr[2][2];
#pragma unroll
      for (int m2 = 0; m2 < 2; ++m2) {
        const int fo = buf + aoff + (2 * q + m2) * 2048;
        afr[m2][0] = *(const bf16x8*)(Sc + fo + sl0);
        afr[m2][1] = *(const bf16x8*)(Sc + fo + sl1);
      }
      if (q == 0) {
#pragma unroll
        for (int fn = 0; fn < 4; ++fn) {
          const int fo = buf + boff + fn * 2048;
          bfr[fn][0] = *(const bf16x8*)(Sc + fo + sl0);
          bfr[fn][1] = *(const bf16x8*)(Sc + fo + sl1);
        }
      }
      if (q == 0)      { if (t + 1 < nt) stA(0, t + 1); }
      else if (q == 1) { if (t + 1 < nt) stA(1, t + 1); }
      else if (q == 2) { if (t + 2 < nt) stB(0, t + 2); }
      else             { if (t + 2 < nt) stB(1, t + 2); }

      __builtin_amdgcn_s_barrier();
      asm volatile("s_waitcnt lgkmcnt(0)" ::: "memory");
      __builtin_amdgcn_sched_barrier(0);
      __builtin_amdgcn_s_setprio(1);
#pragma unroll
      for (int m2 = 0; m2 < 2; ++m2)
#pragma unroll
        for (int fn = 0; fn < 4; ++fn) {
          f32x4 c = acc[2 * q + m2][fn];
          c = __builtin_amdgcn_mfma_f32_16x16x32_bf16(afr[m2][0], bfr[fn][0], c, 0, 0, 0);
          c = __builtin_amdgcn_mfma_f32_16x16x32_bf16(afr[m2][1], bfr[fn][1], c, 0, 0, 0);
          acc[2 * q + m2][fn] = c;
        }
      __builtin_amdgcn_s_setprio(0);
      __builtin_amdgcn_s_barrier();
      __builtin_amdgcn_sched_barrier(0);
    }
    if (t + 1 < nt) {
      if (t + 2 < nt) asm volatile("s_waitcnt vmcnt(4)" ::: "memory");
      else            asm volatile("s_waitcnt vmcnt(0)" ::: "memory");
      __builtin_amdgcn_s_barrier();
      __builtin_amdgcn_sched_barrier(0);
    }
  }

  const int row0 = bm + wm * 128 + l4 * 4;
  const int col0 = bn + wn * 64 + l15;
#pragma unroll
  for (int fm = 0; fm < 8; ++fm) {
    float rs[4] = {1.f, 1.f, 1.f, 1.f};
    if (rowscale) {
#pragma unroll
      for (int i = 0; i < 4; ++i) rs[i] = rowscale[row0 + fm * 16 + i];
    }
#pragma unroll
    for (int fn = 0; fn < 4; ++fn)
#pragma unroll
      for (int i = 0; i < 4; ++i) {
        size_t idx = (size_t)(row0 + fm * 16 + i) * ldc + (col0 + fn * 16);
        float v = acc[fm][fn][i] * rs[i];
        if (OUTF32) ((float*)Cv)[idx] = v;
        else        ((u16*)Cv)[idx] = f2bf(v);
      }
  }
}

// ---------- RoPE cos/sin table ----------
__global__ __launch_bounds__(256) void rope_table(const int* __restrict__ positions,
                                                  float2* __restrict__ tab) {
  int idx = blockIdx.x * 256 + threadIdx.x;
  if (idx >= BTOK * 32) return;
  int bt = idx >> 5, i = idx & 31;
  float invf = powf(10000.0f, -(float)i / 32.0f);
  float ang = (float)positions[bt] * invf;
  tab[idx] = make_float2(cosf(ang), sinf(ang));
}

// ---------- RoPE k_rot -> rot[bt][64] ----------
__global__ __launch_bounds__(256) void rope_k(const u16* __restrict__ proj,
                                              const float2* __restrict__ tab,
                                              u16* __restrict__ rot) {
  int idx = blockIdx.x * 256 + threadIdx.x;   // BT*32
  if (idx >= BTOK * 32) return;
  int bt = idx >> 5, i = idx & 31;
  float2 cs = tab[bt * 32 + i];
  float x1 = bf2f(proj[(size_t)bt * NPROJ + ROT0 + i]);
  float x2 = bf2f(proj[(size_t)bt * NPROJ + ROT0 + 32 + i]);
  rot[bt * 64 + i]      = f2bf(x1 * cs.x - x2 * cs.y);
  rot[bt * 64 + 32 + i] = f2bf(x2 * cs.x + x1 * cs.y);
}

// ---------- job table ----------
__device__ const int8_t JOB_QT[24] = {15,15,7,14,14,13,13,6,12,12,11,11,5,10,10,9,9,4,8,8,3,2,1,0};
__device__ const int8_t JOB_PC[24] = { 0, 1,2, 0, 1, 0, 1,2, 0, 1, 0, 1,2, 0, 1,0,1,2,0,1,2,2,2,2};

// ---------- causal flash attention v8: RoPE-on-Q folded into Q-fragment load ----------
// Q rot halves live in the same lane: kk=4 (x1, cols 128-159), kk=5 (x2, cols 160-191),
// element j has rope index i = l4*8+j. Applied once per block (not per tile).
__global__ __launch_bounds__(256, 2) void attn_fwd8(const u16* __restrict__ Q,
                                                    const float2* __restrict__ tab,
                                                    const u16* __restrict__ Rot,
                                                    const u16* __restrict__ KV,
                                                    u16* __restrict__ O,
                                                    u16* __restrict__ Opart,
                                                    float2* __restrict__ ml) {
  __shared__ __align__(16) u16 Ks[64 * 192];     // 24KB, XOR-swizzled
  __shared__ __align__(16) u16 Vs[64 * 128];     // 16KB, tr-subtile, identity key order
  __shared__ __align__(16) u16 Ps[4][32][72];    // 18KB, rows=q, cols=key (identity)

  const int tid = threadIdx.x, lane = tid & 63, wave = tid >> 6;
  const int l15 = lane & 15, l4 = lane >> 4;
  const int jobrank = blockIdx.x >> 5;
  const int bh = blockIdx.x & 31;
  const int qt = JOB_QT[jobrank];
  const int piece = JOB_PC[jobrank];
  const int q0 = qt * 128;
  const int b = bh >> 4, h = bh & 15;
  const int wq0 = q0 + wave * 32;

  bf16x8 qf[2][6];
#pragma unroll
  for (int m = 0; m < 2; ++m) {
    const u16* qp = Q + (size_t)(b * TT + wq0 + m * 16 + l15) * 3072 + h * 192 + l4 * 8;
#pragma unroll
    for (int kk = 0; kk < 6; ++kk) qf[m][kk] = *(const bf16x8*)(qp + kk * 32);
    // in-register RoPE on the rot fragments (kk=4: x1, kk=5: x2)
    const float2* tp = tab + (size_t)(b * TT + wq0 + m * 16 + l15) * 32 + l4 * 8;
    union { bf16x8 v; u16 e[8]; } a4, a5, o4, o5;
    a4.v = qf[m][4]; a5.v = qf[m][5];
#pragma unroll
    for (int j = 0; j < 8; ++j) {
      float2 cs = tp[j];
      float x1 = bf2f(a4.e[j]), x2 = bf2f(a5.e[j]);
      o4.e[j] = f2bf(x1 * cs.x - x2 * cs.y);
      o5.e[j] = f2bf(x2 * cs.x + x1 * cs.y);
    }
    qf[m][4] = o4.v; qf[m][5] = o5.v;
  }

  const int kt0 = (piece == 1) ? (qt + 1) : 0;
  const int kt1 = (piece == 0) ? (qt + 1) : (2 * qt + 2);

  const u16* kvb  = KV + (size_t)(b * TT) * 4096 + h * 256;
  const u16* rotb = Rot + (size_t)(b * TT) * 64;
  const u16* kp[6];
  int kstep[6];
#pragma unroll
  for (int j = 0; j < 6; ++j) {
    int o = (wave * 6 + j) * 1024 + lane * 16;
    int row = o / 384, col = o % 384;
    int scol = col ^ ((row & 7) << 4);
    if (scol < 256) { kp[j] = kvb + row * 4096 + (scol >> 1);          kstep[j] = 64 * 4096; }
    else            { kp[j] = rotb + row * 64 + ((scol >> 1) - 128);   kstep[j] = 64 * 64; }
    kp[j] += (size_t)kt0 * kstep[j];
  }
  int vsrc[4];
#pragma unroll
  for (int j = 0; j < 4; ++j) {
    int lam = (wave * 4 + j) * 512 + lane * 8;
    int kap = ((lam >> 6) & 15) * 4 + ((lam >> 4) & 3);
    int key = ((kap >> 5) & 1) * 32 + ((kap >> 2) & 3) * 8 + ((kap >> 4) & 1) * 4 + (kap & 3);
    int dv  = (lam >> 10) * 16 + (lam & 15);
    vsrc[j] = key * 4096 + dv;
  }
  const u16* Vbase = KV + (size_t)(b * TT) * 4096 + h * 256 + 128;
  u16* KsW = Ks + (wave * 6) * 512;
  u16* VsW = Vs + (wave * 4) * 512;
  const unsigned vs_base = (unsigned)(uintptr_t)(&Vs[0]);

  f32x4 o_acc[2][8] = {};
  float m_r[2], l_r[2];
#pragma unroll
  for (int m = 0; m < 2; ++m) { m_r[m] = -INFINITY; l_r[m] = 0.f; }

  for (int kt = kt0; kt < kt1; ++kt) {
    __syncthreads();
    const u16* Vt = Vbase + (size_t)(kt * 64) * 4096;
#pragma unroll
    for (int j = 0; j < 6; ++j) { gload_lds16(kp[j], KsW + j * 512); kp[j] += kstep[j]; }
#pragma unroll
    for (int j = 0; j < 4; ++j) gload_lds16(Vt + vsrc[j], VsW + j * 512);
    __syncthreads();

    if (kt * 64 > wq0 + 31) continue;
    const int kt64 = kt * 64;

    // ---- S^T = K Q^T (swapped operands) ----
    f32x4 s[2][4] = {};
    __builtin_amdgcn_s_setprio(1);
#pragma unroll
    for (int n = 0; n < 4; ++n) {
      const int krow = n * 16 + l15;
      const int swz = (l15 & 7) << 3;
#pragma unroll
      for (int kk = 0; kk < 6; ++kk) {
        bf16x8 kb = *(const bf16x8*)&Ks[krow * 192 + ((kk * 32 + l4 * 8) ^ swz)];
        s[0][n] = __builtin_amdgcn_mfma_f32_16x16x32_bf16(kb, qf[0][kk], s[0][n], 0, 0, 0);
        s[1][n] = __builtin_amdgcn_mfma_f32_16x16x32_bf16(kb, qf[1][kk], s[1][n], 0, 0, 0);
      }
    }
    __builtin_amdgcn_s_setprio(0);

    // ---- online softmax ----
#pragma unroll
    for (int m = 0; m < 2; ++m) {
      const int qrow = wq0 + m * 16 + l15;
      const bool needmask = (kt64 + 63) > (wq0 + m * 16);
      if (needmask) {
#pragma unroll
        for (int n = 0; n < 4; ++n)
#pragma unroll
          for (int i = 0; i < 4; ++i)
            if (kt64 + n * 16 + l4 * 4 + i > qrow) s[m][n][i] = -INFINITY;
      }
      float pmax = -INFINITY;
#pragma unroll
      for (int n = 0; n < 4; ++n)
#pragma unroll
        for (int i = 0; i < 4; ++i) pmax = fmaxf(pmax, s[m][n][i]);
      pmax = fmaxf(pmax, __shfl_xor(pmax, 16));
      pmax = fmaxf(pmax, __shfl_xor(pmax, 32));

      if (!__all(pmax - m_r[m] <= 8.f)) {        // defer-max (THR=8)
        float mn = fmaxf(m_r[m], pmax);
        float alpha = __expf(m_r[m] - mn);
        m_r[m] = mn;
        l_r[m] *= alpha;
        float ab[4];
#pragma unroll
        for (int i = 0; i < 4; ++i) ab[i] = __shfl(alpha, l4 * 4 + i);
#pragma unroll
        for (int n = 0; n < 8; ++n)
#pragma unroll
          for (int i = 0; i < 4; ++i) o_acc[m][n][i] *= ab[i];
      }

      float psum = 0.f;
#pragma unroll
      for (int n = 0; n < 4; ++n) {
        float p0 = __expf(s[m][n][0] - m_r[m]);
        float p1 = __expf(s[m][n][1] - m_r[m]);
        float p2 = __expf(s[m][n][2] - m_r[m]);
        float p3 = __expf(s[m][n][3] - m_r[m]);
        psum += (p0 + p1) + (p2 + p3);
        union { uint2 d; u16 e[4]; } pw;
        pw.e[0] = f2bf(p0); pw.e[1] = f2bf(p1);
        pw.e[2] = f2bf(p2); pw.e[3] = f2bf(p3);
        *(uint2*)&Ps[wave][m * 16 + l15][n * 16 + l4 * 4] = pw.d;
      }
      psum += __shfl_xor(psum, 16);
      psum += __shfl_xor(psum, 32);
      l_r[m] += psum;
    }

    asm volatile("s_waitcnt lgkmcnt(0)" ::: "memory");
    __builtin_amdgcn_sched_barrier(0);

    // ---- O += P V ----
#pragma unroll
    for (int kk = 0; kk < 2; ++kk) {
      bf16x8 pa[2];
      pa[0] = *(const bf16x8*)&Ps[wave][l15][kk * 32 + l4 * 8];
      pa[1] = *(const bf16x8*)&Ps[wave][16 + l15][kk * 32 + l4 * 8];
      const unsigned va = vs_base + kk * 1024 + lane * 8;
#pragma unroll
      for (int g = 0; g < 2; ++g) {
        union { uint2 u; bf16x4 b; } lo[4], hi[4];
#pragma unroll
        for (int n = 0; n < 4; ++n) {
          unsigned a0 = va + (g * 4 + n) * 2048;
          asm volatile("ds_read_b64_tr_b16 %0, %1" : "=v"(lo[n].u) : "v"(a0));
          asm volatile("ds_read_b64_tr_b16 %0, %1 offset:512" : "=v"(hi[n].u) : "v"(a0));
        }
        asm volatile("s_waitcnt lgkmcnt(0)" ::: "memory");
        __builtin_amdgcn_sched_barrier(0);
        __builtin_amdgcn_s_setprio(1);
#pragma unroll
        for (int n = 0; n < 4; ++n) {
          bf16x8 vb = __builtin_shufflevector(lo[n].b, hi[n].b, 0, 1, 2, 3, 4, 5, 6, 7);
          o_acc[0][g * 4 + n] = __builtin_amdgcn_mfma_f32_16x16x32_bf16(pa[0], vb, o_acc[0][g * 4 + n], 0, 0, 0);
          o_acc[1][g * 4 + n] = __builtin_amdgcn_mfma_f32_16x16x32_bf16(pa[1], vb, o_acc[1][g * 4 + n], 0, 0, 0);
        }
        __builtin_amdgcn_s_setprio(0);
      }
    }
  }

  if (piece == 2) {
#pragma unroll
    for (int m = 0; m < 2; ++m) {
      float inv = 1.f / l_r[m];
      float li[4];
#pragma unroll
      for (int i = 0; i < 4; ++i) li[i] = __shfl(inv, l4 * 4 + i);
#pragma unroll
      for (int n = 0; n < 8; ++n)
#pragma unroll
        for (int i = 0; i < 4; ++i) {
          int r = wq0 + m * 16 + l4 * 4 + i;
          O[(size_t)(b * TT + r) * 2048 + h * 128 + n * 16 + l15] = f2bf(o_acc[m][n][i] * li[i]);
        }
    }
  } else {
    const size_t pidx = ((size_t)(qt - 8) * 32 + bh) * 2 + piece;
    u16* op = Opart + pidx * (128 * 128);
    float2* mlp = ml + pidx * 128;
#pragma unroll
    for (int m = 0; m < 2; ++m)
#pragma unroll
      for (int n = 0; n < 8; ++n)
#pragma unroll
        for (int i = 0; i < 4; ++i)
          op[(wave * 32 + m * 16 + l4 * 4 + i) * 128 + n * 16 + l15] = f2bf(o_acc[m][n][i]);
    if (l4 == 0) {
#pragma unroll
      for (int m = 0; m < 2; ++m)
        mlp[wave * 32 + m * 16 + l15] = make_float2(m_r[m], l_r[m]);
    }
  }
}

// ---------- combine split pieces ----------
__global__ __launch_bounds__(256) void attn_combine(const u16* __restrict__ Opart,
                                                    const float2* __restrict__ ml,
                                                    u16* __restrict__ O) {
  int gid = blockIdx.x * 256 + threadIdx.x;
  int dvseg = gid & 15;
  int row = (gid >> 4) & 127;
  int bh = (gid >> 11) & 31;
  int qt8 = gid >> 16;
  size_t i1 = ((size_t)qt8 * 32 + bh) * 2;
  float2 ml1 = ml[i1 * 128 + row], ml2 = ml[(i1 + 1) * 128 + row];
  float m = fmaxf(ml1.x, ml2.x);
  float w1 = __expf(ml1.x - m), w2 = __expf(ml2.x - m);
  float inv = 1.f / (w1 * ml1.y + w2 * ml2.y);
  union { f32x4 q; u16 e[8]; } a, bq, w;
  a.q  = *(const f32x4*)&Opart[i1 * 16384 + row * 128 + dvseg * 8];
  bq.q = *(const f32x4*)&Opart[(i1 + 1) * 16384 + row * 128 + dvseg * 8];
#pragma unroll
  for (int j = 0; j < 8; ++j)
    w.e[j] = f2bf((w1 * bf2f(a.e[j]) + w2 * bf2f(bq.e[j])) * inv);
  int b = bh >> 4, h = bh & 15;
  int r = 1024 + qt8 * 128 + row;
  *(f32x4*)&O[(size_t)(b * TT + r) * 2048 + h * 128 + dvseg * 8] = w.q;
}

extern "C" void kernel_launch(void* const* d_in, const int* in_sizes, int n_in,
                              void* d_out, int out_size, void* d_ws, size_t ws_size,
                              hipStream_t stream) {
  (void)in_sizes; (void)n_in; (void)out_size; (void)ws_size;
  const float* x         = (const float*)d_in[0];
  const int*   positions = (const int*)d_in[2];
  const float* wqa       = (const float*)d_in[3];
  const float* qa_scale  = (const float*)d_in[4];
  const float* wqb       = (const float*)d_in[5];
  const float* wkva      = (const float*)d_in[6];
  const float* kva_scale = (const float*)d_in[7];
  const float* wkvb      = (const float*)d_in[8];
  const float* wo        = (const float*)d_in[9];
  float* out = (float*)d_out;

  char* wsp = (char*)d_ws;
  auto alloc = [&](size_t bytes) {
    char* p = wsp; wsp += (bytes + 255) & ~(size_t)255; return p;
  };
  u16* xb      = (u16*)alloc((size_t)BTOK * HIDDIM * 2);       // x bf16; reused as attn O
  u16* proj_t  = (u16*)alloc((size_t)NPROJ * HIDDIM * 2);      // [wqa_t | wkva_t | pad]
  u16* wqb_t   = (u16*)alloc((size_t)3072 * QLRANK * 2);       // qa_scale*qscale folded
  u16* wkvb_t  = (u16*)alloc((size_t)4096 * KVRANK * 2);       // kva_scale folded
  u16* wo_t    = (u16*)alloc((size_t)HIDDIM * HIDDIM * 2);
  u16* proj    = (u16*)alloc((size_t)BTOK * NPROJ * 2);        // [qlat | ckv | rot | pad]
  u16* q       = (u16*)alloc((size_t)BTOK * 3072 * 2);
  u16* kv      = (u16*)alloc((size_t)BTOK * 4096 * 2);
  u16* rot     = (u16*)alloc((size_t)BTOK * 64 * 2);           // roped k_rot
  float2* tab  = (float2*)alloc((size_t)BTOK * 32 * 8);
  float* invq  = (float*)alloc((size_t)BTOK * 4);
  float* invkv = (float*)alloc((size_t)BTOK * 4);
  float2* mlbuf= (float2*)alloc((size_t)8 * 32 * 2 * 128 * 8);
  u16* ao = xb;          // xb dead after proj GEMM
  u16* Opart = proj;     // proj dead after gemm2/gemm4/rope_k

  dim3 blk(256);
  dim3 blk512(512);
  const float qscale = 0.07216878364870322f;   // 192^-0.5, folded into wqb

  cvt_f32_bf16<<<(BTOK * HIDDIM / 8 + 255) / 256, blk, 0, stream>>>(x, xb, BTOK * HIDDIM);
  {
    dim3 tb(32, 8);
    transpose_w<<<dim3(HIDDIM / 32, QLRANK / 32), tb, 0, stream>>>(wqa, proj_t, HIDDIM, QLRANK, QLRANK, 1.f, nullptr);
    transpose_w<<<dim3(HIDDIM / 32, (NPROJ - CKV0) / 32), tb, 0, stream>>>(wkva, proj_t + (size_t)CKV0 * HIDDIM, HIDDIM, 576, NPROJ - CKV0, 1.f, nullptr);
    transpose_w<<<dim3(QLRANK / 32, 3072 / 32), tb, 0, stream>>>(wqb, wqb_t, QLRANK, 3072, 3072, qscale, qa_scale);
    transpose_w<<<dim3(KVRANK / 32, 4096 / 32), tb, 0, stream>>>(wkvb, wkvb_t, KVRANK, 4096, 4096, 1.f, kva_scale);
    transpose_w<<<dim3(HIDDIM / 32, HIDDIM / 32), tb, 0, stream>>>(wo, wo_t, HIDDIM, HIDDIM, HIDDIM, 1.f, nullptr);
  }
  rope_table<<<(BTOK * 32 + 255) / 256, blk, 0, stream>>>(positions, tab);

  // fused projection (576 blocks @128^2, counted-vmcnt) — r12-proven config
  gemm_bt<0><<<dim3(NPROJ / 128, BTOK / 128), blk, 0, stream>>>(xb, HIDDIM, proj_t, proj, NPROJ, nullptr, NPROJ, HIDDIM);

  row_invrms<QLRANK><<<BTOK, blk, 0, stream>>>(proj, NPROJ, invq);
  row_invrms<KVRANK><<<BTOK, blk, 0, stream>>>(proj + CKV0, NPROJ, invkv);

  // big-grid GEMMs on the 8-phase kernel (192 / 256 blocks @256^2), XCD-swizzled
  gemm8p<0><<<dim3(3072 / 256, BTOK / 256), blk512, 0, stream>>>(proj, NPROJ, wqb_t, q, 3072, invq, QLRANK);
  gemm8p<0><<<dim3(4096 / 256, BTOK / 256), blk512, 0, stream>>>(proj + CKV0, NPROJ, wkvb_t, kv, 4096, invkv, KVRANK);

  rope_k<<<(BTOK * 32 + 255) / 256, blk, 0, stream>>>(proj, tab, rot);

  attn_fwd8<<<dim3(24 * 32), blk, 0, stream>>>(q, tab, rot, kv, ao, Opart, mlbuf);
  attn_combine<<<(8 * 32 * 128 * 16) / 256, blk, 0, stream>>>(Opart, mlbuf, ao);

  // output projection (512 blocks @128^2, counted-vmcnt)
  gemm_bt<1><<<dim3(HIDDIM / 128, BTOK / 128), blk, 0, stream>>>(ao, HIDDIM, wo_t, out, HIDDIM, nullptr, HIDDIM, HIDDIM);
}